// Round 1
// baseline (1671.758 us; speedup 1.0000x reference)
//
#include <hip/hip_runtime.h>
#include <hip/hip_bf16.h>

// GIN: N=100000 nodes, E=1.6M edges, G=64 graphs, D=128, L=4 layers.
// Strategy: CSR-gather aggregation (no feature atomics), fp32 LDS-tiled GEMMs
// (in-place over row blocks), BN stats/apply passes, pooling fused into BN-apply.

#define N_NODES   100000
#define N_EDGES   1600000
#define N_GRAPHS  64
#define DIM       128
#define N_LAYERS  4
#define CLS_IN    640
#define CLS_HID   256
#define N_CLASSES 10
#define LRELU_SLOPE 0.01f
#define BN_EPS_F    1e-5f

#define SCAN_B  256
#define SCAN_NB 391   // ceil(100000/256)

__device__ __forceinline__ float lrelu(float x) { return x > 0.f ? x : LRELU_SLOPE * x; }

// ---------------- initial one-hot features ----------------
__global__ void k_build_x(const int* __restrict__ deg, float* __restrict__ x) {
    int gid = blockIdx.x * blockDim.x + threadIdx.x;   // one per float4
    if (gid >= N_NODES * 32) return;
    int i = gid >> 5, q = gid & 31;
    int d = deg[i];
    float4 v = make_float4(0.f, 0.f, 0.f, 0.f);
    if ((d >> 2) == q) ((float*)&v)[d & 3] = 1.0f;
    ((float4*)x)[gid] = v;
}

// ---------------- CSR build ----------------
__global__ void k_count(const int* __restrict__ dst, int* __restrict__ counts) {
    int e = blockIdx.x * blockDim.x + threadIdx.x;
    if (e < N_EDGES) atomicAdd(&counts[dst[e]], 1);
}

__global__ void k_scan1(const int* __restrict__ counts, int* __restrict__ indptr,
                        int* __restrict__ bsums) {
    __shared__ int sh[SCAN_B];
    int t = threadIdx.x, i = blockIdx.x * SCAN_B + t;
    int v = (i < N_NODES) ? counts[i] : 0;
    sh[t] = v; __syncthreads();
    for (int off = 1; off < SCAN_B; off <<= 1) {
        int add = (t >= off) ? sh[t - off] : 0;
        __syncthreads();
        sh[t] += add;
        __syncthreads();
    }
    if (i < N_NODES) indptr[i] = sh[t] - v;           // local exclusive
    if (t == SCAN_B - 1) bsums[blockIdx.x] = sh[t];   // block total
}

__global__ void k_scan2(const int* __restrict__ bsums, int* __restrict__ boffs) {
    __shared__ int sh[512];
    int t = threadIdx.x;
    int v = (t < SCAN_NB) ? bsums[t] : 0;
    sh[t] = v; __syncthreads();
    for (int off = 1; off < 512; off <<= 1) {
        int add = (t >= off) ? sh[t - off] : 0;
        __syncthreads();
        sh[t] += add;
        __syncthreads();
    }
    if (t < SCAN_NB) boffs[t + 1] = sh[t];   // exclusive offsets, boffs[SCAN_NB]=total
    if (t == 0) boffs[0] = 0;
}

__global__ void k_scan3(int* __restrict__ indptr, const int* __restrict__ boffs) {
    int i = blockIdx.x * SCAN_B + threadIdx.x;
    if (i < N_NODES) indptr[i] += boffs[blockIdx.x];
    if (i == 0) indptr[N_NODES] = boffs[SCAN_NB];
}

__global__ void k_fill(const int* __restrict__ src, const int* __restrict__ dst,
                       const int* __restrict__ indptr, int* __restrict__ cursor,
                       int* __restrict__ csr) {
    int e = blockIdx.x * blockDim.x + threadIdx.x;
    if (e >= N_EDGES) return;
    int d = dst[e];
    int pos = indptr[d] + atomicAdd(&cursor[d], 1);
    csr[pos] = src[e];
}

// ---------------- neighbor aggregation: one wave per node ----------------
__global__ void __launch_bounds__(256) k_gather(const float* __restrict__ h,
                                                const int* __restrict__ indptr,
                                                const int* __restrict__ csr,
                                                float* __restrict__ agg) {
    int wave = (blockIdx.x * blockDim.x + threadIdx.x) >> 6;   // node id
    int lane = threadIdx.x & 63;
    if (wave >= N_NODES) return;
    int beg = indptr[wave], end = indptr[wave + 1];
    const float2* hp = (const float2*)h;
    float2 acc = make_float2(0.f, 0.f);
    int e = beg;
    for (; e + 1 < end; e += 2) {
        int u0 = csr[e], u1 = csr[e + 1];
        float2 v0 = hp[u0 * 64 + lane];
        float2 v1 = hp[u1 * 64 + lane];
        acc.x += v0.x + v1.x;
        acc.y += v0.y + v1.y;
    }
    if (e < end) {
        int u = csr[e];
        float2 v = hp[u * 64 + lane];
        acc.x += v.x; acc.y += v.y;
    }
    ((float2*)agg)[wave * 64 + lane] = acc;
}

// ---------------- GEMM: C[r][n] = act((s*A + A2)[r][:] @ W + bias) ----------------
// BM=64 rows/block, BN=128 (full), BK=64; K-major A tile; in-place safe (C rows == A rows,
// fully staged to LDS before any write).
#define BM 64
#define BK 64
__global__ void __launch_bounds__(256) k_gemm(const float* A, const float* A2,
                                              const float* __restrict__ epsv, int layer,
                                              const float* __restrict__ W,
                                              const float* __restrict__ bias,
                                              float* C, int do_lrelu) {
    __shared__ float As[BK][BM + 4];    // stride 68 floats = 17*16B: float4-aligned
    __shared__ float Bs[BK][DIM];
    const int t = threadIdx.x;
    const int row0 = blockIdx.x * BM;
    const float s = A2 ? (1.0f + epsv[layer]) : 1.0f;
    const int cx = t & 15;    // cols cx*8 .. cx*8+7
    const int cy = t >> 4;    // rows cy*4 .. cy*4+3

    float acc[4][8];
#pragma unroll
    for (int i = 0; i < 4; ++i)
#pragma unroll
        for (int j = 0; j < 8; ++j) acc[i][j] = 0.f;

    for (int kc = 0; kc < DIM; kc += BK) {
        // stage A (64 rows x 64 k), transposed to K-major; lanes span rows -> conflict-free
        {
            int k0 = 4 * (t >> 6);    // 0,4,8,12 (wave-uniform)
            int row = t & 63;
            int r = row0 + row;
#pragma unroll
            for (int j = 0; j < 4; ++j) {
                int kl = k0 + 16 * j;
                float4 a = make_float4(0.f, 0.f, 0.f, 0.f);
                if (r < N_NODES) {
                    float4 av = *(const float4*)&A[(size_t)r * DIM + kc + kl];
                    if (A2) {
                        float4 a2 = *(const float4*)&A2[(size_t)r * DIM + kc + kl];
                        a = make_float4(s * av.x + a2.x, s * av.y + a2.y,
                                        s * av.z + a2.z, s * av.w + a2.w);
                    } else a = av;
                }
                As[kl + 0][row] = a.x;
                As[kl + 1][row] = a.y;
                As[kl + 2][row] = a.z;
                As[kl + 3][row] = a.w;
            }
        }
        // stage B (W chunk: 64 k x 128 n), already K-major in memory
        {
            int n0 = 4 * (t & 31);
            int kr = t >> 5;          // 0..7
#pragma unroll
            for (int j = 0; j < 8; ++j) {
                int kl = kr + 8 * j;
                *(float4*)&Bs[kl][n0] = *(const float4*)&W[(kc + kl) * DIM + n0];
            }
        }
        __syncthreads();
#pragma unroll 16
        for (int k = 0; k < BK; ++k) {
            float4 a  = *(const float4*)&As[k][cy * 4];
            float4 b0 = *(const float4*)&Bs[k][cx * 8];
            float4 b1 = *(const float4*)&Bs[k][cx * 8 + 4];
            float av[4] = {a.x, a.y, a.z, a.w};
            float bv[8] = {b0.x, b0.y, b0.z, b0.w, b1.x, b1.y, b1.z, b1.w};
#pragma unroll
            for (int i = 0; i < 4; ++i)
#pragma unroll
                for (int j = 0; j < 8; ++j) acc[i][j] += av[i] * bv[j];
        }
        __syncthreads();
    }
    // epilogue
    float bv[8];
#pragma unroll
    for (int j = 0; j < 8; ++j) bv[j] = bias[cx * 8 + j];
#pragma unroll
    for (int i = 0; i < 4; ++i) {
        int r = row0 + cy * 4 + i;
        if (r >= N_NODES) continue;
        float o[8];
#pragma unroll
        for (int j = 0; j < 8; ++j) {
            float v = acc[i][j] + bv[j];
            o[j] = do_lrelu ? lrelu(v) : v;
        }
        *(float4*)&C[(size_t)r * DIM + cx * 8]     = make_float4(o[0], o[1], o[2], o[3]);
        *(float4*)&C[(size_t)r * DIM + cx * 8 + 4] = make_float4(o[4], o[5], o[6], o[7]);
    }
}

// ---------------- BN stats (column sums / sumsq) ----------------
#define BNS_ROWS 256
__global__ void __launch_bounds__(256) k_bn_stats(const float* __restrict__ h,
                                                  float* __restrict__ stats) {
    int f = threadIdx.x & 127;
    int half = threadIdx.x >> 7;
    int r0 = blockIdx.x * BNS_ROWS + half * (BNS_ROWS / 2);
    float s1 = 0.f, s2 = 0.f;
    for (int i = 0; i < BNS_ROWS / 2; ++i) {
        int r = r0 + i;
        if (r >= N_NODES) break;
        float v = h[(size_t)r * DIM + f];
        s1 += v; s2 += v * v;
    }
    atomicAdd(&stats[f], s1);
    atomicAdd(&stats[DIM + f], s2);
}

__global__ void k_bn_final(float* __restrict__ stats, const float* __restrict__ bn_g,
                           const float* __restrict__ bn_b, int layer) {
    int f = threadIdx.x;   // 128 threads
    float mean = stats[f] * (1.0f / N_NODES);
    float var  = stats[DIM + f] * (1.0f / N_NODES) - mean * mean;
    float inv  = rsqrtf(var + BN_EPS_F);
    float sc = bn_g[layer * DIM + f] * inv;
    float sh = bn_b[layer * DIM + f] - mean * sc;
    stats[f] = sc;
    stats[DIM + f] = sh;
}

// ---------------- BN apply + lrelu + fused segment-sum pooling ----------------
// mode do_bn=0: pool src directly (used for zs[0]); do_bn=1: z=lrelu(bn(src)) -> dst, pool z.
#define POOL_ROWS 128
__global__ void __launch_bounds__(256) k_bnpool(const float* __restrict__ src,
                                                float* __restrict__ dst,
                                                const float* __restrict__ stats,
                                                const int* __restrict__ batch,
                                                float* __restrict__ pooled,
                                                int colOff, int do_bn) {
    int f = threadIdx.x & 127;
    int half = threadIdx.x >> 7;
    int r0 = blockIdx.x * POOL_ROWS + half * (POOL_ROWS / 2);
    float sc = 1.f, sh = 0.f;
    if (do_bn) { sc = stats[f]; sh = stats[DIM + f]; }
    int curg = -1;
    float acc = 0.f;
    for (int i = 0; i < POOL_ROWS / 2; ++i) {
        int r = r0 + i;
        if (r >= N_NODES) break;
        float v = src[(size_t)r * DIM + f];
        if (do_bn) {
            v = lrelu(v * sc + sh);
            dst[(size_t)r * DIM + f] = v;
        }
        int g = batch[r];
        if (g != curg) {
            if (curg >= 0) atomicAdd(&pooled[curg * CLS_IN + colOff + f], acc);
            curg = g; acc = 0.f;
        }
        acc += v;
    }
    if (curg >= 0) atomicAdd(&pooled[curg * CLS_IN + colOff + f], acc);
}

// ---------------- classifier head: one block per graph ----------------
__global__ void __launch_bounds__(256) k_classifier(const float* __restrict__ pooled,
                                                    const float* __restrict__ Wc1,
                                                    const float* __restrict__ bc1,
                                                    const float* __restrict__ Wc2,
                                                    const float* __restrict__ bc2,
                                                    float* __restrict__ out) {
    __shared__ float p[CLS_IN];
    __shared__ float hh[CLS_HID];
    int g = blockIdx.x, t = threadIdx.x;
    for (int j = t; j < CLS_IN; j += 256) p[j] = lrelu(pooled[g * CLS_IN + j]);
    __syncthreads();
    float acc = bc1[t];
    for (int k = 0; k < CLS_IN; ++k) acc += p[k] * Wc1[k * CLS_HID + t];
    hh[t] = lrelu(acc);
    __syncthreads();
    if (t < N_CLASSES) {
        float a2 = bc2[t];
        for (int k = 0; k < CLS_HID; ++k) a2 += hh[k] * Wc2[k * N_CLASSES + t];
        out[g * N_CLASSES + t] = a2;
    }
}

extern "C" void kernel_launch(void* const* d_in, const int* in_sizes, int n_in,
                              void* d_out, int out_size, void* d_ws, size_t ws_size,
                              hipStream_t stream) {
    const int*   deg   = (const int*)d_in[0];
    const int*   edges = (const int*)d_in[1];
    const int*   srcv  = edges;
    const int*   dstv  = edges + N_EDGES;
    const int*   batch = (const int*)d_in[2];
    const float* epsv  = (const float*)d_in[3];
    const float* W1    = (const float*)d_in[4];
    const float* b1    = (const float*)d_in[5];
    const float* W2    = (const float*)d_in[6];
    const float* b2    = (const float*)d_in[7];
    const float* bn_g  = (const float*)d_in[8];
    const float* bn_b  = (const float*)d_in[9];
    const float* Wc1   = (const float*)d_in[10];
    const float* bc1   = (const float*)d_in[11];
    const float* Wc2   = (const float*)d_in[12];
    const float* bc2   = (const float*)d_in[13];

    char* ws = (char*)d_ws;
    const size_t BUFB = (size_t)N_NODES * DIM * 4;          // 51,200,000
    float* buf0   = (float*)(ws);
    float* buf1   = (float*)(ws + BUFB);
    float* pooled = (float*)(ws + 2 * BUFB);                               // 163,840 B
    float* stats  = (float*)(ws + 2 * BUFB + 163840);                      // 1,024 B
    int*   boffs  = (int*)  (ws + 2 * BUFB + 164864);                      // 2,048 B
    int*   bsums  = (int*)  (ws + 2 * BUFB + 166912);                      // 2,048 B
    int*   indptr = (int*)  (ws + 2 * BUFB + 168960);                      // 400,384 B
    int*   counts = (int*)  (ws + 2 * BUFB + 569344);                      // 400,384 B
    int*   csr    = (int*)  (ws + 2 * BUFB + 969728);                      // 6,400,000 B

    hipMemsetAsync(pooled, 0, N_GRAPHS * CLS_IN * 4, stream);
    hipMemsetAsync(counts, 0, N_NODES * 4, stream);

    k_build_x<<<(N_NODES * 32 + 255) / 256, 256, 0, stream>>>(deg, buf0);
    k_count<<<(N_EDGES + 255) / 256, 256, 0, stream>>>(dstv, counts);
    k_scan1<<<SCAN_NB, SCAN_B, 0, stream>>>(counts, indptr, bsums);
    k_scan2<<<1, 512, 0, stream>>>(bsums, boffs);
    k_scan3<<<SCAN_NB, SCAN_B, 0, stream>>>(indptr, boffs);
    hipMemsetAsync(counts, 0, N_NODES * 4, stream);   // reuse as fill cursor
    k_fill<<<(N_EDGES + 255) / 256, 256, 0, stream>>>(srcv, dstv, indptr, counts, csr);

    // pool zs[0] = one-hot features
    k_bnpool<<<(N_NODES + POOL_ROWS - 1) / POOL_ROWS, 256, 0, stream>>>(
        buf0, nullptr, nullptr, batch, pooled, 0, 0);

    const int gemm_grid = (N_NODES + BM - 1) / BM;   // 1563
    for (int l = 0; l < N_LAYERS; ++l) {
        k_gather<<<(N_NODES * 64 + 255) / 256, 256, 0, stream>>>(buf0, indptr, csr, buf1);
        // buf1 = lrelu(((1+eps)*buf0 + buf1) @ W1 + b1)   (in-place over row blocks)
        k_gemm<<<gemm_grid, 256, 0, stream>>>(buf0, buf1, epsv, l,
                                              W1 + l * DIM * DIM, b1 + l * DIM, buf1, 1);
        // buf1 = buf1 @ W2 + b2
        k_gemm<<<gemm_grid, 256, 0, stream>>>(buf1, nullptr, epsv, l,
                                              W2 + l * DIM * DIM, b2 + l * DIM, buf1, 0);
        hipMemsetAsync(stats, 0, 2 * DIM * 4, stream);
        k_bn_stats<<<(N_NODES + BNS_ROWS - 1) / BNS_ROWS, 256, 0, stream>>>(buf1, stats);
        k_bn_final<<<1, DIM, 0, stream>>>(stats, bn_g, bn_b, l);
        // buf0 = lrelu(bn(buf1)); pooled[:, 128*(l+1):] += segment_sum
        k_bnpool<<<(N_NODES + POOL_ROWS - 1) / POOL_ROWS, 256, 0, stream>>>(
            buf1, buf0, stats, batch, pooled, DIM * (l + 1), 1);
    }

    k_classifier<<<N_GRAPHS, 256, 0, stream>>>(pooled, Wc1, bc1, Wc2, bc2, (float*)d_out);
}

// Round 2
// 874.271 us; speedup vs baseline: 1.9122x; 1.9122x over previous
//
#include <hip/hip_runtime.h>
#include <hip/hip_bf16.h>

// GIN: N=100000, E=1.6M, G=64, D=128, L=4.
// R2: bf16 feature storage (halves all streaming bytes), bf16 MFMA GEMMs
// (16x16x32, 128x128 tile, BN-stats fused into GEMM2 epilogue), gather with
// fused (1+eps)*h_in and lane-cooperative CSR index loads.

#define N_NODES   100000
#define N_EDGES   1600000
#define N_GRAPHS  64
#define DIM       128
#define N_LAYERS  4
#define CLS_IN    640
#define CLS_HID   256
#define N_CLASSES 10
#define LRELU_SLOPE 0.01f
#define BN_EPS_F    1e-5f

#define SCAN_B  256
#define SCAN_NB 391   // ceil(100000/256)

typedef __attribute__((ext_vector_type(8))) short bf16x8;
typedef __attribute__((ext_vector_type(4))) float f32x4;

__device__ __forceinline__ float lrelu(float x) { return x > 0.f ? x : LRELU_SLOPE * x; }

__device__ __forceinline__ uint pack2(float x, float y) {
    uint a = __float_as_uint(x), b = __float_as_uint(y);
    a = (a + 0x7FFFu + ((a >> 16) & 1u)) >> 16;
    b = (b + 0x7FFFu + ((b >> 16) & 1u)) >> 16;
    return a | (b << 16);
}
__device__ __forceinline__ float2 unpack2(uint v) {
    return make_float2(__uint_as_float(v << 16), __uint_as_float(v & 0xFFFF0000u));
}

// ---------------- weight convert: W[k][n] fp32 -> Wt[n][k] bf16 ----------------
__global__ void k_convert_w(const float* __restrict__ W1, const float* __restrict__ W2,
                            ushort* __restrict__ W1t, ushort* __restrict__ W2t) {
    int gid = blockIdx.x * blockDim.x + threadIdx.x;   // 8 * 16384
    if (gid >= 8 * DIM * DIM) return;
    int mat = gid >> 14, idx = gid & 16383;
    int k = idx >> 7, n = idx & 127;
    const float* src = (mat < 4) ? (W1 + mat * DIM * DIM) : (W2 + (mat - 4) * DIM * DIM);
    ushort* dst = (mat < 4) ? (W1t + mat * DIM * DIM) : (W2t + (mat - 4) * DIM * DIM);
    uint a = __float_as_uint(src[k * DIM + n]);
    dst[n * DIM + k] = (ushort)((a + 0x7FFFu + ((a >> 16) & 1u)) >> 16);
}

// ---------------- initial one-hot features (bf16) ----------------
__global__ void k_build_x(const int* __restrict__ deg, uint* __restrict__ x) {
    int gid = blockIdx.x * blockDim.x + threadIdx.x;   // one per uint (2 bf16)
    if (gid >= N_NODES * 64) return;
    int i = gid >> 6, c = gid & 63;
    int d = deg[i];
    uint v = 0;
    if ((d >> 1) == c) v = 0x3F80u << (16 * (d & 1));
    x[gid] = v;
}

// zs[0] pooling = per-graph degree histogram
__global__ void k_deg_pool(const int* __restrict__ deg, const int* __restrict__ batch,
                           float* __restrict__ pooled) {
    int i = blockIdx.x * blockDim.x + threadIdx.x;
    if (i < N_NODES) atomicAdd(&pooled[batch[i] * CLS_IN + deg[i]], 1.0f);
}

// ---------------- CSR build ----------------
__global__ void k_count(const int* __restrict__ dst, int* __restrict__ counts) {
    int e = blockIdx.x * blockDim.x + threadIdx.x;
    if (e < N_EDGES) atomicAdd(&counts[dst[e]], 1);
}

__global__ void k_scan1(const int* __restrict__ counts, int* __restrict__ indptr,
                        int* __restrict__ bsums) {
    __shared__ int sh[SCAN_B];
    int t = threadIdx.x, i = blockIdx.x * SCAN_B + t;
    int v = (i < N_NODES) ? counts[i] : 0;
    sh[t] = v; __syncthreads();
    for (int off = 1; off < SCAN_B; off <<= 1) {
        int add = (t >= off) ? sh[t - off] : 0;
        __syncthreads();
        sh[t] += add;
        __syncthreads();
    }
    if (i < N_NODES) indptr[i] = sh[t] - v;
    if (t == SCAN_B - 1) bsums[blockIdx.x] = sh[t];
}

__global__ void k_scan2(const int* __restrict__ bsums, int* __restrict__ boffs) {
    __shared__ int sh[512];
    int t = threadIdx.x;
    int v = (t < SCAN_NB) ? bsums[t] : 0;
    sh[t] = v; __syncthreads();
    for (int off = 1; off < 512; off <<= 1) {
        int add = (t >= off) ? sh[t - off] : 0;
        __syncthreads();
        sh[t] += add;
        __syncthreads();
    }
    if (t < SCAN_NB) boffs[t + 1] = sh[t];
    if (t == 0) boffs[0] = 0;
}

__global__ void k_scan3(int* __restrict__ indptr, const int* __restrict__ boffs) {
    int i = blockIdx.x * SCAN_B + threadIdx.x;
    if (i < N_NODES) indptr[i] += boffs[blockIdx.x];
    if (i == 0) indptr[N_NODES] = boffs[SCAN_NB];
}

__global__ void k_fill(const int* __restrict__ src, const int* __restrict__ dst,
                       const int* __restrict__ indptr, int* __restrict__ cursor,
                       int* __restrict__ csr) {
    int e = blockIdx.x * blockDim.x + threadIdx.x;
    if (e >= N_EDGES) return;
    int d = dst[e];
    int pos = indptr[d] + atomicAdd(&cursor[d], 1);
    csr[pos] = src[e];
}

// ---------------- gather: out = (1+eps)*h + sum_{src->node} h[src]  (bf16) ----------------
__global__ void __launch_bounds__(256) k_gather(const uint* __restrict__ h,
                                                const int* __restrict__ indptr,
                                                const int* __restrict__ csr,
                                                uint* __restrict__ out,
                                                const float* __restrict__ epsv, int layer) {
    int node = (blockIdx.x * blockDim.x + threadIdx.x) >> 6;
    int lane = threadIdx.x & 63;
    if (node >= N_NODES) return;
    float s = 1.0f + epsv[layer];
    float2 own = unpack2(h[node * 64 + lane]);
    float ax = s * own.x, ay = s * own.y;
    int beg = indptr[node], end = indptr[node + 1];
    for (int base = beg; base < end; base += 64) {
        int cnt = end - base; if (cnt > 64) cnt = 64;
        int myid = (lane < cnt) ? csr[base + lane] : 0;
        int j = 0;
        for (; j + 4 <= cnt; j += 4) {
            int u0 = __shfl(myid, j), u1 = __shfl(myid, j + 1);
            int u2 = __shfl(myid, j + 2), u3 = __shfl(myid, j + 3);
            uint v0 = h[u0 * 64 + lane], v1 = h[u1 * 64 + lane];
            uint v2 = h[u2 * 64 + lane], v3 = h[u3 * 64 + lane];
            float2 f0 = unpack2(v0), f1 = unpack2(v1), f2 = unpack2(v2), f3 = unpack2(v3);
            ax += (f0.x + f1.x) + (f2.x + f3.x);
            ay += (f0.y + f1.y) + (f2.y + f3.y);
        }
        for (; j < cnt; ++j) {
            int u = __shfl(myid, j);
            float2 f = unpack2(h[u * 64 + lane]);
            ax += f.x; ay += f.y;
        }
    }
    out[node * 64 + lane] = pack2(ax, ay);
}

// ---------------- bf16 MFMA GEMM: C = act(A @ Wt^T + bias), in-place safe ----------------
// A: [N][128] bf16, Wt: [128 n][128 k] bf16. 128x128 tile, K=128 single stage.
// stats != nullptr: atomically accumulate column sum/sumsq (pre-activation, incl bias).
#define GEMM_LDS_BYTES 69632
__global__ void __launch_bounds__(256) k_gemm(const ushort* __restrict__ A,
                                              const ushort* __restrict__ Wt,
                                              const float* __restrict__ bias,
                                              ushort* __restrict__ C,
                                              float* __restrict__ stats,
                                              int do_lrelu) {
    __shared__ char pool[GEMM_LDS_BYTES];
    ushort* As = (ushort*)pool;             // [128][136]
    ushort* Ws = (ushort*)(pool + 34816);   // [128][136]
    float*  Cs = (float*)pool;              // [128][132] (aliases As/Ws after sync)
    const int t = threadIdx.x;
    const int row0 = blockIdx.x * 128;
    {   // stage A tile + weight tile (coalesced 16B chunks)
        int r = t >> 1, hh = t & 1;
        uint4* l = (uint4*)(As + r * 136 + hh * 64);
        if (row0 + r < N_NODES) {
            const uint4* g = (const uint4*)(A + (size_t)(row0 + r) * DIM + hh * 64);
#pragma unroll
            for (int k = 0; k < 8; ++k) l[k] = g[k];
        } else {
            uint4 z = make_uint4(0, 0, 0, 0);
#pragma unroll
            for (int k = 0; k < 8; ++k) l[k] = z;
        }
        const uint4* gw = (const uint4*)(Wt + r * DIM + hh * 64);
        uint4* lw = (uint4*)(Ws + r * 136 + hh * 64);
#pragma unroll
        for (int k = 0; k < 8; ++k) lw[k] = gw[k];
    }
    __syncthreads();
    const int lane = t & 63, wave = t >> 6;
    const int q = lane >> 4, m = lane & 15;
    const int R = (wave >> 1) * 64, Cb = (wave & 1) * 64;
    f32x4 acc[4][4] = {};
#pragma unroll
    for (int ks = 0; ks < 4; ++ks) {
        bf16x8 a[4], b[4];
#pragma unroll
        for (int i = 0; i < 4; ++i)
            a[i] = *(const bf16x8*)(As + (R + i * 16 + m) * 136 + ks * 32 + q * 8);
#pragma unroll
        for (int j = 0; j < 4; ++j)
            b[j] = *(const bf16x8*)(Ws + (Cb + j * 16 + m) * 136 + ks * 32 + q * 8);
#pragma unroll
        for (int i = 0; i < 4; ++i)
#pragma unroll
            for (int j = 0; j < 4; ++j)
                acc[i][j] = __builtin_amdgcn_mfma_f32_16x16x32_bf16(a[i], b[j], acc[i][j], 0, 0, 0);
    }
    __syncthreads();   // all LDS reads done; safe to alias Cs
    float biasr[4];
#pragma unroll
    for (int j = 0; j < 4; ++j) biasr[j] = bias[Cb + j * 16 + m];
#pragma unroll
    for (int i = 0; i < 4; ++i)
#pragma unroll
        for (int j = 0; j < 4; ++j)
#pragma unroll
            for (int r = 0; r < 4; ++r)
                Cs[(R + i * 16 + q * 4 + r) * 132 + Cb + j * 16 + m] = acc[i][j][r] + biasr[j];
    __syncthreads();
    if (stats != nullptr && t < DIM) {
        int rows = N_NODES - row0; if (rows > 128) rows = 128;
        float s1 = 0.f, s2 = 0.f;
        for (int r = 0; r < rows; ++r) { float v = Cs[r * 132 + t]; s1 += v; s2 += v * v; }
        atomicAdd(&stats[t], s1);
        atomicAdd(&stats[DIM + t], s2);
    }
    {   // read back, activation, bf16 pack, coalesced store
        int r = t >> 1, hh = t & 1;
        if (row0 + r < N_NODES) {
            uint4* out = (uint4*)(C + (size_t)(row0 + r) * DIM + hh * 64);
#pragma unroll
            for (int k = 0; k < 8; ++k) {
                float4 v0 = *(const float4*)(Cs + r * 132 + hh * 64 + k * 8);
                float4 v1 = *(const float4*)(Cs + r * 132 + hh * 64 + k * 8 + 4);
                if (do_lrelu) {
                    v0.x = lrelu(v0.x); v0.y = lrelu(v0.y); v0.z = lrelu(v0.z); v0.w = lrelu(v0.w);
                    v1.x = lrelu(v1.x); v1.y = lrelu(v1.y); v1.z = lrelu(v1.z); v1.w = lrelu(v1.w);
                }
                uint4 o;
                o.x = pack2(v0.x, v0.y); o.y = pack2(v0.z, v0.w);
                o.z = pack2(v1.x, v1.y); o.w = pack2(v1.z, v1.w);
                out[k] = o;
            }
        }
    }
}

// ---------------- BN finalize: stats -> scale/shift ----------------
__global__ void k_bn_final(float* __restrict__ stats, const float* __restrict__ bn_g,
                           const float* __restrict__ bn_b, int layer) {
    int f = threadIdx.x;   // 128 threads
    float mean = stats[f] * (1.0f / N_NODES);
    float var  = stats[DIM + f] * (1.0f / N_NODES) - mean * mean;
    float inv  = rsqrtf(var + BN_EPS_F);
    float sc = bn_g[layer * DIM + f] * inv;
    float sh = bn_b[layer * DIM + f] - mean * sc;
    stats[f] = sc;
    stats[DIM + f] = sh;
}

// ---------------- BN apply + lrelu + fused pooling (bf16 in/out) ----------------
#define PROWS 128
__global__ void __launch_bounds__(256) k_bnpool(const uint* __restrict__ src,
                                                uint* __restrict__ dst,
                                                const float* __restrict__ stats,
                                                const int* __restrict__ batch,
                                                float* __restrict__ pooled, int colOff) {
    int c = threadIdx.x & 63;           // uint column (2 bf16 features)
    int chunk = threadIdx.x >> 6;       // 0..3
    int r0 = blockIdx.x * PROWS + chunk * (PROWS / 4);
    float sc0 = stats[2 * c], sc1 = stats[2 * c + 1];
    float sh0 = stats[DIM + 2 * c], sh1 = stats[DIM + 2 * c + 1];
    int curg = -1;
    float a0 = 0.f, a1 = 0.f;
    for (int i = 0; i < PROWS / 4; ++i) {
        int r = r0 + i;
        if (r >= N_NODES) break;
        float2 v = unpack2(src[r * 64 + c]);
        float x0 = lrelu(v.x * sc0 + sh0);
        float x1 = lrelu(v.y * sc1 + sh1);
        dst[r * 64 + c] = pack2(x0, x1);
        int g = batch[r];
        if (g != curg) {
            if (curg >= 0) {
                atomicAdd(&pooled[curg * CLS_IN + colOff + 2 * c], a0);
                atomicAdd(&pooled[curg * CLS_IN + colOff + 2 * c + 1], a1);
            }
            curg = g; a0 = 0.f; a1 = 0.f;
        }
        a0 += x0; a1 += x1;
    }
    if (curg >= 0) {
        atomicAdd(&pooled[curg * CLS_IN + colOff + 2 * c], a0);
        atomicAdd(&pooled[curg * CLS_IN + colOff + 2 * c + 1], a1);
    }
}

// ---------------- classifier head (fp32): one block per graph ----------------
__global__ void __launch_bounds__(256) k_classifier(const float* __restrict__ pooled,
                                                    const float* __restrict__ Wc1,
                                                    const float* __restrict__ bc1,
                                                    const float* __restrict__ Wc2,
                                                    const float* __restrict__ bc2,
                                                    float* __restrict__ out) {
    __shared__ float p[CLS_IN];
    __shared__ float hh[CLS_HID];
    int g = blockIdx.x, t = threadIdx.x;
    for (int j = t; j < CLS_IN; j += 256) p[j] = lrelu(pooled[g * CLS_IN + j]);
    __syncthreads();
    float acc = bc1[t];
    for (int k = 0; k < CLS_IN; ++k) acc += p[k] * Wc1[k * CLS_HID + t];
    hh[t] = lrelu(acc);
    __syncthreads();
    if (t < N_CLASSES) {
        float a2 = bc2[t];
        for (int k = 0; k < CLS_HID; ++k) a2 += hh[k] * Wc2[k * N_CLASSES + t];
        out[g * N_CLASSES + t] = a2;
    }
}

extern "C" void kernel_launch(void* const* d_in, const int* in_sizes, int n_in,
                              void* d_out, int out_size, void* d_ws, size_t ws_size,
                              hipStream_t stream) {
    const int*   deg   = (const int*)d_in[0];
    const int*   edges = (const int*)d_in[1];
    const int*   srcv  = edges;
    const int*   dstv  = edges + N_EDGES;
    const int*   batch = (const int*)d_in[2];
    const float* epsv  = (const float*)d_in[3];
    const float* W1    = (const float*)d_in[4];
    const float* b1    = (const float*)d_in[5];
    const float* W2    = (const float*)d_in[6];
    const float* b2    = (const float*)d_in[7];
    const float* bn_g  = (const float*)d_in[8];
    const float* bn_b  = (const float*)d_in[9];
    const float* Wc1   = (const float*)d_in[10];
    const float* bc1   = (const float*)d_in[11];
    const float* Wc2   = (const float*)d_in[12];
    const float* bc2   = (const float*)d_in[13];

    char* ws = (char*)d_ws;
    const size_t BUFB = (size_t)N_NODES * DIM * 2;   // 25,600,000 B (bf16)
    size_t off = 0;
    ushort* buf0   = (ushort*)(ws + off); off += BUFB;
    ushort* buf1   = (ushort*)(ws + off); off += BUFB;
    ushort* W1t    = (ushort*)(ws + off); off += 4 * DIM * DIM * 2;   // 131072
    ushort* W2t    = (ushort*)(ws + off); off += 4 * DIM * DIM * 2;
    float*  pooled = (float*)(ws + off);  off += N_GRAPHS * CLS_IN * 4;  // 163840
    float*  statsA = (float*)(ws + off);  off += 4 * 2 * DIM * 4;        // 4096
    int*    boffs  = (int*)(ws + off);    off += (SCAN_NB + 1 + 7) * 4;
    int*    bsums  = (int*)(ws + off);    off += (SCAN_NB + 7) * 4;
    int*    indptr = (int*)(ws + off);    off += (N_NODES + 8) * 4;
    int*    counts = (int*)(ws + off);    off += (N_NODES + 8) * 4;
    int*    csr    = (int*)(ws + off);    off += (size_t)N_EDGES * 4;

    hipMemsetAsync(pooled, 0, N_GRAPHS * CLS_IN * 4, stream);
    hipMemsetAsync(statsA, 0, 4 * 2 * DIM * 4, stream);
    hipMemsetAsync(counts, 0, N_NODES * 4, stream);

    k_convert_w<<<(8 * DIM * DIM + 255) / 256, 256, 0, stream>>>(W1, W2, W1t, W2t);
    k_build_x<<<(N_NODES * 64 + 255) / 256, 256, 0, stream>>>(deg, (uint*)buf0);
    k_deg_pool<<<(N_NODES + 255) / 256, 256, 0, stream>>>(deg, batch, pooled);

    k_count<<<(N_EDGES + 255) / 256, 256, 0, stream>>>(dstv, counts);
    k_scan1<<<SCAN_NB, SCAN_B, 0, stream>>>(counts, indptr, bsums);
    k_scan2<<<1, 512, 0, stream>>>(bsums, boffs);
    k_scan3<<<SCAN_NB, SCAN_B, 0, stream>>>(indptr, boffs);
    hipMemsetAsync(counts, 0, N_NODES * 4, stream);   // reuse as fill cursor
    k_fill<<<(N_EDGES + 255) / 256, 256, 0, stream>>>(srcv, dstv, indptr, counts, csr);

    const int gemm_grid = (N_NODES + 127) / 128;   // 782
    for (int l = 0; l < N_LAYERS; ++l) {
        float* stats = statsA + l * 2 * DIM;
        k_gather<<<(N_NODES * 64 + 255) / 256, 256, 0, stream>>>(
            (const uint*)buf0, indptr, csr, (uint*)buf1, epsv, l);
        k_gemm<<<gemm_grid, 256, 0, stream>>>(buf1, W1t + l * DIM * DIM, b1 + l * DIM,
                                              buf1, nullptr, 1);
        k_gemm<<<gemm_grid, 256, 0, stream>>>(buf1, W2t + l * DIM * DIM, b2 + l * DIM,
                                              buf1, stats, 0);
        k_bn_final<<<1, DIM, 0, stream>>>(stats, bn_g, bn_b, l);
        k_bnpool<<<(N_NODES + PROWS - 1) / PROWS, 256, 0, stream>>>(
            (const uint*)buf1, (uint*)buf0, stats, batch, pooled, DIM * (l + 1));
    }

    k_classifier<<<N_GRAPHS, 256, 0, stream>>>(pooled, Wc1, bc1, Wc2, bc2, (float*)d_out);
}